// Round 8
// baseline (3736.625 us; speedup 1.0000x reference)
//
#include <hip/hip_runtime.h>
#include <hip/hip_bf16.h>
#include <stdint.h>

// ---------------- constants ----------------
#define T_TOK 8192          // B*S tokens
#define DM    768
#define NH    12
#define DH    64
#define SEQ   1024
#define NBH   96            // B*NH
#define NMEM  3072
#define NUP   4608          // 768 (Q) + 768 (K) + 3072 (mem)
#define ALPHA 0.1f
#define EPS   1e-5f
#define NSTEPS 12
#define PAD   72            // LDS row stride (us) for attention 64-wide tiles
#define SPLITK 2            // down-GEMM split-K (proven r7: halves partial traffic)

typedef unsigned short us;
typedef __bf16 bf16x8 __attribute__((ext_vector_type(8)));
typedef float  f32x4  __attribute__((ext_vector_type(4)));

__device__ __forceinline__ us f2bf(float f) {          // RNE float->bf16
  uint32_t u = __builtin_bit_cast(uint32_t, f);
  u += 0x7fffu + ((u >> 16) & 1u);
  return (us)(u >> 16);
}

__device__ __forceinline__ f32x4 mfma16(bf16x8 a, bf16x8 b, f32x4 c) {
  return __builtin_amdgcn_mfma_f32_16x16x32_bf16(a, b, c, 0, 0, 0);
}

// async global->LDS, 16B per lane. LDS dest must be base + lane*16 in lane order.
__device__ __forceinline__ void gld16(const void* g, void* l) {
  __builtin_amdgcn_global_load_lds(
      (const __attribute__((address_space(1))) void*)(uintptr_t)g,
      (__attribute__((address_space(3))) void*)(uint32_t)(uintptr_t)l,
      16, 0, 0);
}

__device__ __forceinline__ float block_sum(float v, float* sb, int tid) {
#pragma unroll
  for (int d = 32; d >= 1; d >>= 1) v += __shfl_xor(v, d);
  __syncthreads();
  if ((tid & 63) == 0) sb[tid >> 6] = v;
  __syncthreads();
  return sb[0] + sb[1] + sb[2] + sb[3];
}

// ---------------- pack weights to bf16 (once per launch) ----------------
__global__ __launch_bounds__(256) void pack_w(const float* __restrict__ Wq,
                                              const float* __restrict__ Wk,
                                              const float* __restrict__ xi,
                                              us* __restrict__ Wup, us* __restrict__ WdT) {
  int idx = blockIdx.x * 256 + threadIdx.x;
  if (idx >= NUP * DM) return;
  int r = idx / DM, d = idx - r * DM;
  float v = (r < 768) ? Wq[idx] : (r < 1536 ? Wk[idx - 768 * DM] : xi[idx - 1536 * DM]);
  us h = f2bf(v);
  Wup[idx] = h;
  WdT[(size_t)d * NUP + r] = h;
}

// ---------------- LayerNorm fwd (only before step 0; later steps fuse LN into update) ----------
__global__ __launch_bounds__(256) void ln_fwd(const float* __restrict__ X,
                                              const float* __restrict__ gamma,
                                              const float* __restrict__ delta,
                                              us* __restrict__ g_bf,
                                              float* __restrict__ meanb, float* __restrict__ rstdb) {
  int t = blockIdx.x, tid = threadIdx.x;
  const float* x = X + (size_t)t * DM;
  __shared__ float sb[4];
  float v0 = x[tid], v1 = x[tid + 256], v2 = x[tid + 512];
  float mean = block_sum(v0 + v1 + v2, sb, tid) * (1.0f / DM);
  float d0 = v0 - mean, d1 = v1 - mean, d2 = v2 - mean;
  float var = block_sum(d0 * d0 + d1 * d1 + d2 * d2, sb, tid) * (1.0f / DM);
  float rstd = rsqrtf(var + EPS);
  float gm = gamma[0];
  us* go = g_bf + (size_t)t * DM;
  go[tid]       = f2bf(gm * d0 * rstd + delta[tid]);
  go[tid + 256] = f2bf(gm * d1 * rstd + delta[tid + 256]);
  go[tid + 512] = f2bf(gm * d2 * rstd + delta[tid + 512]);
  if (tid == 0) { meanb[t] = mean; rstdb[t] = rstd; }
}

// ---------------- GEMM: C = A * B^T (bf16 in, fp32 acc) ----------------
// FROZEN from round 5 (best measured: 91 us up-proj, FETCH 45 MB).
// 128x128, 4 waves, 2-slot dbuf, 1 barrier/K-tile, involution swizzle,
// swapped-operand MFMA epilogue. Seven schedule variants measured 24-27%
// MfmaUtil (latency-bound, all pipes <30%); do not re-tune.
template <int MODE>
__global__ __launch_bounds__(256, 4) void gemm_bt(const us* __restrict__ A, const us* __restrict__ B,
                                                  int Kstride, int kchunk, us* __restrict__ QKout,
                                                  us* __restrict__ Dout, float* __restrict__ Gout) {
  __shared__ us As[2 * 128 * 32];   // 16 KiB: [slot][row 128][kslot 0..3][8 us]
  __shared__ us Bs[2 * 128 * 32];   // 16 KiB
  int tid = threadIdx.x;
  int w = tid >> 6, lane = tid & 63, lm = lane & 15, lq = lane >> 4;
  int wm = (w >> 1) * 64, wn = (w & 1) * 64;   // 2x2 wave grid; per-wave C = 64x64

  int m0 = blockIdx.x * 128, n0 = blockIdx.y * 128;
  int kbeg = blockIdx.z * kchunk;
  int NT = kchunk >> 5;             // K tiles of 32 (even): up 24, down 72

  int sr  = tid >> 2;
  int k8s = (tid & 3) ^ ((tid >> 3) & 3);
  const us* pa = A + (size_t)(m0 + sr) * Kstride + kbeg + k8s * 8;
  const us* pb = B + (size_t)(n0 + sr) * Kstride + kbeg + k8s * 8;
  const size_t hstep = (size_t)64 * Kstride;
  us* dA0 = &As[tid * 8];           // linear LDS dest: slot*4096 + half*2048 + tid*8
  us* dB0 = &Bs[tid * 8];

  int kx = (lq ^ ((lm >> 1) & 3)) * 8;     // row bits [2:1] == lm bits [2:1]
  const us* Ar = As + (wm + lm) * 32 + kx; // frag mt at Ar[S*4096 + mt*512]
  const us* Br = Bs + (wn + lm) * 32 + kx; // frag nt at Br[S*4096 + nt*512]

  f32x4 zero4 = {0.f, 0.f, 0.f, 0.f};
  f32x4 acc[4][4];
#pragma unroll
  for (int i = 0; i < 4; i++)
#pragma unroll
    for (int j = 0; j < 4; j++) acc[i][j] = zero4;

#define STAGE(S, T) { gld16(pa + (size_t)(T) * 32,         dA0 + (S) * 4096);        \
                      gld16(pa + (size_t)(T) * 32 + hstep, dA0 + (S) * 4096 + 2048); \
                      gld16(pb + (size_t)(T) * 32,         dB0 + (S) * 4096);        \
                      gld16(pb + (size_t)(T) * 32 + hstep, dB0 + (S) * 4096 + 2048); }

  STAGE(0, 0);
  asm volatile("s_waitcnt vmcnt(0)" ::: "memory");
  __builtin_amdgcn_s_barrier();

#define ITER(T, S) {                                                            \
    if ((T) + 1 < NT) STAGE((S) ^ 1, (T) + 1);                                  \
    bf16x8 af_[4], bf_[4];                                                      \
    _Pragma("unroll") for (int x = 0; x < 4; x++)                               \
      af_[x] = *(const bf16x8*)(Ar + (S) * 4096 + x * 512);                     \
    _Pragma("unroll") for (int x = 0; x < 4; x++)                               \
      bf_[x] = *(const bf16x8*)(Br + (S) * 4096 + x * 512);                     \
    _Pragma("unroll") for (int mt = 0; mt < 4; mt++)                            \
      _Pragma("unroll") for (int nt = 0; nt < 4; nt++)                          \
        acc[mt][nt] = mfma16(bf_[nt], af_[mt], acc[mt][nt]);   /* swapped */    \
    if ((T) + 1 < NT) {                                                         \
      asm volatile("s_waitcnt lgkmcnt(0)" ::: "memory");                        \
      asm volatile("s_waitcnt vmcnt(0)" ::: "memory");                          \
      __builtin_amdgcn_s_barrier();                                             \
    }                                                                           \
  }

  for (int t = 0; t < NT; t += 2) {
    ITER(t,     0);
    ITER(t + 1, 1);
  }
#undef ITER
#undef STAGE

  // ---- epilogue (swapped layout): thread holds C[row][col..col+3] with
  // row = m0+wm+mt*16+lm, col = n0+wn+nt*16+lq*4. Branch on n0 is
  // block-uniform (128-col blocks never straddle the 1536 boundary).
  int cb = wn + lq * 4;
  if (MODE == 0 && n0 < 1536) {
#pragma unroll
    for (int mt = 0; mt < 4; mt++) {
      us* rowp = QKout + (size_t)(m0 + wm + mt * 16 + lm) * 1536 + n0 + cb;
#pragma unroll
      for (int nt = 0; nt < 4; nt++) {
        f32x4 v = acc[mt][nt];
        uint2 p;
        p.x = (uint32_t)f2bf(v[0]) | ((uint32_t)f2bf(v[1]) << 16);
        p.y = (uint32_t)f2bf(v[2]) | ((uint32_t)f2bf(v[3]) << 16);
        *(uint2*)(rowp + nt * 16) = p;
      }
    }
  } else if (MODE == 0) {
#pragma unroll
    for (int mt = 0; mt < 4; mt++) {
      us* rowp = Dout + (size_t)(m0 + wm + mt * 16 + lm) * NUP + n0 + cb;
#pragma unroll
      for (int nt = 0; nt < 4; nt++) {
        f32x4 v = acc[mt][nt];
        uint2 p;
        p.x = (uint32_t)f2bf(fmaxf(v[0], 0.f)) | ((uint32_t)f2bf(fmaxf(v[1], 0.f)) << 16);
        p.y = (uint32_t)f2bf(fmaxf(v[2], 0.f)) | ((uint32_t)f2bf(fmaxf(v[3], 0.f)) << 16);
        *(uint2*)(rowp + nt * 16) = p;
      }
    }
  } else {
    float* Gz = Gout + (size_t)blockIdx.z * T_TOK * DM;
#pragma unroll
    for (int mt = 0; mt < 4; mt++) {
      float* rowp = Gz + (size_t)(m0 + wm + mt * 16 + lm) * DM + n0 + cb;
#pragma unroll
      for (int nt = 0; nt < 4; nt++)
        *(f32x4*)(rowp + nt * 16) = acc[mt][nt];
    }
  }
}

// ---------------- transpose QK -> per-head Qt/Kt (dh-major, key contiguous) ----------------
__global__ __launch_bounds__(256) void transpose_qk(const us* __restrict__ QK,
                                                    us* __restrict__ Qt, us* __restrict__ Kt) {
  int bh = blockIdx.x, kt = blockIdx.y, which = blockIdx.z;
  int b = bh / NH, h = bh - b * NH;
  int tid = threadIdx.x;
  __shared__ us tile[64][72];
  int c0 = h * 64 + (which ? 768 : 0);
  us* dst = (which ? Kt : Qt) + (size_t)bh * 64 * 1024;
#pragma unroll
  for (int r = 0; r < 2; r++) {
    int key = r * 32 + (tid >> 3); int yb = (tid & 7) * 8;
    *(bf16x8*)&tile[key][yb] =
        *(const bf16x8*)&QK[(size_t)(b * SEQ + kt * 64 + key) * 1536 + c0 + yb];
  }
  __syncthreads();
#pragma unroll
  for (int r = 0; r < 2; r++) {
    int lin = r * 256 + tid; int y = lin >> 3; int kb = (lin & 7) * 8;
    __align__(16) us tmp[8];
#pragma unroll
    for (int j = 0; j < 8; j++) tmp[j] = tile[kb + j][y];
    *(bf16x8*)&dst[(size_t)y * 1024 + kt * 64 + kb] = *(bf16x8*)tmp;
  }
}

// ---------------- attention pass 1: Oq = softmax(beta QK^T) K (+lse) ----------------
// ROUND-8: QBLK=128 (was 64). Each block owns 128 queries; each wave keeps
// TWO 64-row sub-tiles' Q fragments in registers and runs softmax+PV twice
// per staged K/Kt tile, reusing the per-wave Ps scratch sequentially
// (within-wave DS ordering; no extra barrier). Halves staging bytes and
// barrier count per unit work. Grid NBH x 8 = 768 blocks = exactly 1.0
// round at 3 blocks/CU (LDS 45 KB).
// No online max: |beta*A| << 1 (g is LayerNormed), exp cannot overflow.
__global__ __launch_bounds__(256) void attn_fwd(const us* __restrict__ QK, const us* __restrict__ Ktg,
                                                const float* __restrict__ beta,
                                                us* __restrict__ Dbuf, float* __restrict__ lse) {
  __shared__ us Qs[128 * PAD];
  __shared__ us Ks[64 * PAD];
  __shared__ us Kts[64 * PAD];
  __shared__ us Ps[4 * 16 * PAD];
  int bh = blockIdx.x, qt = blockIdx.y;    // qt: 0..7, 128 queries each
  int b = bh / NH, h = bh - b * NH;
  int tid = threadIdx.x, w = tid >> 6, lane = tid & 63, lm = lane & 15, lq = lane >> 4;
  float betah = beta[h];
#pragma unroll
  for (int r = 0; r < 4; r++) {
    int row = r * 32 + (tid >> 3); int yb = (tid & 7) * 8;
    *(bf16x8*)&Qs[row * PAD + yb] =
        *(const bf16x8*)&QK[(size_t)(b * SEQ + qt * 128 + row) * 1536 + h * 64 + yb];
  }
  __syncthreads();
  bf16x8 aq0[2], aq1[2];
#pragma unroll
  for (int s = 0; s < 2; s++) {
    aq0[s] = *(const bf16x8*)&Qs[(s * 64 + w * 16 + lm) * PAD + lq * 8];
    aq1[s] = *(const bf16x8*)&Qs[(s * 64 + w * 16 + lm) * PAD + 32 + lq * 8];
  }
  f32x4 zero = {0.f, 0.f, 0.f, 0.f};
  f32x4 O[2][4];
  float lacc[2][4];
#pragma unroll
  for (int s = 0; s < 2; s++)
#pragma unroll
    for (int i = 0; i < 4; i++) { O[s][i] = zero; lacc[s][i] = 0.f; }
  us* pw = &Ps[w * 16 * PAD];

  for (int kc = 0; kc < SEQ; kc += 64) {
    __syncthreads();
#pragma unroll
    for (int r = 0; r < 2; r++) {
      int row = r * 32 + (tid >> 3); int yb = (tid & 7) * 8;
      *(bf16x8*)&Ks[row * PAD + yb] =
          *(const bf16x8*)&QK[(size_t)(b * SEQ + kc + row) * 1536 + 768 + h * 64 + yb];
      int lin = r * 256 + tid; int y = lin >> 3; int kb = (lin & 7) * 8;
      *(bf16x8*)&Kts[y * PAD + kb] =
          *(const bf16x8*)&Ktg[(size_t)(bh * 64 + y) * 1024 + kc + kb];
    }
    __syncthreads();
#pragma unroll
    for (int s = 0; s < 2; s++) {
#pragma unroll
      for (int kk = 0; kk < 4; kk++) {
        f32x4 sv = mfma16(aq0[s], *(const bf16x8*)&Ks[(kk * 16 + lm) * PAD + lq * 8], zero);
        sv = mfma16(aq1[s], *(const bf16x8*)&Ks[(kk * 16 + lm) * PAD + 32 + lq * 8], sv);
#pragma unroll
        for (int r = 0; r < 4; r++) {
          float p = __expf(betah * sv[r]);
          lacc[s][r] += p;
          pw[(lq * 4 + r) * PAD + kk * 16 + lm] = f2bf(p);
        }
      }
      bf16x8 pa0 = *(const bf16x8*)&pw[lm * PAD + lq * 8];
      bf16x8 pa1 = *(const bf16x8*)&pw[lm * PAD + 32 + lq * 8];
#pragma unroll
      for (int nt = 0; nt < 4; nt++) {
        O[s][nt] = mfma16(pa0, *(const bf16x8*)&Kts[(nt * 16 + lm) * PAD + lq * 8], O[s][nt]);
        O[s][nt] = mfma16(pa1, *(const bf16x8*)&Kts[(nt * 16 + lm) * PAD + 32 + lq * 8], O[s][nt]);
      }
    }
  }
#pragma unroll
  for (int s = 0; s < 2; s++) {
    float l[4];
#pragma unroll
    for (int r = 0; r < 4; r++) {
      float v = lacc[s][r];
      v += __shfl_xor(v, 1); v += __shfl_xor(v, 2);
      v += __shfl_xor(v, 4); v += __shfl_xor(v, 8);
      l[r] = v;
    }
    float inv[4];
#pragma unroll
    for (int r = 0; r < 4; r++) inv[r] = 1.f / l[r];
#pragma unroll
    for (int nt = 0; nt < 4; nt++)
#pragma unroll
      for (int r = 0; r < 4; r++) {
        int q = qt * 128 + s * 64 + w * 16 + lq * 4 + r;
        Dbuf[(size_t)(b * SEQ + q) * NUP + h * 64 + nt * 16 + lm] = f2bf(O[s][nt][r] * inv[r]);
      }
    if (lm == 0) {
#pragma unroll
      for (int r = 0; r < 4; r++)
        lse[bh * SEQ + qt * 128 + s * 64 + w * 16 + lq * 4 + r] = __logf(l[r]);
    }
  }
}

// ---------------- attention pass 2: Ok = P^T Q using stored lse ----------------
// ROUND-8: KBLK=128 (two key sub-tiles per block), same amortization as fwd.
__global__ __launch_bounds__(256) void attn_bwd(const us* __restrict__ QK, const us* __restrict__ Qtg,
                                                const float* __restrict__ lse,
                                                const float* __restrict__ beta,
                                                us* __restrict__ Dbuf) {
  __shared__ us Ks2[128 * PAD];
  __shared__ us Qs2[64 * PAD];
  __shared__ us Qts[64 * PAD];
  __shared__ us Ps[4 * 16 * PAD];
  int bh = blockIdx.x, kt = blockIdx.y;    // kt: 0..7, 128 keys each
  int b = bh / NH, h = bh - b * NH;
  int tid = threadIdx.x, w = tid >> 6, lane = tid & 63, lm = lane & 15, lq = lane >> 4;
  float betah = beta[h];
#pragma unroll
  for (int r = 0; r < 4; r++) {
    int row = r * 32 + (tid >> 3); int yb = (tid & 7) * 8;
    *(bf16x8*)&Ks2[row * PAD + yb] =
        *(const bf16x8*)&QK[(size_t)(b * SEQ + kt * 128 + row) * 1536 + 768 + h * 64 + yb];
  }
  __syncthreads();
  bf16x8 ak0[2], ak1[2];
#pragma unroll
  for (int s = 0; s < 2; s++) {
    ak0[s] = *(const bf16x8*)&Ks2[(s * 64 + w * 16 + lm) * PAD + lq * 8];
    ak1[s] = *(const bf16x8*)&Ks2[(s * 64 + w * 16 + lm) * PAD + 32 + lq * 8];
  }
  f32x4 zero = {0.f, 0.f, 0.f, 0.f};
  f32x4 O[2][4];
#pragma unroll
  for (int s = 0; s < 2; s++)
#pragma unroll
    for (int i = 0; i < 4; i++) O[s][i] = zero;
  us* pw = &Ps[w * 16 * PAD];

  for (int qc = 0; qc < SEQ; qc += 64) {
    __syncthreads();
#pragma unroll
    for (int r = 0; r < 2; r++) {
      int row = r * 32 + (tid >> 3); int yb = (tid & 7) * 8;
      *(bf16x8*)&Qs2[row * PAD + yb] =
          *(const bf16x8*)&QK[(size_t)(b * SEQ + qc + row) * 1536 + h * 64 + yb];
      int lin = r * 256 + tid; int y = lin >> 3; int qb = (lin & 7) * 8;
      *(bf16x8*)&Qts[y * PAD + qb] =
          *(const bf16x8*)&Qtg[(size_t)(bh * 64 + y) * 1024 + qc + qb];
    }
    __syncthreads();
#pragma unroll
    for (int s = 0; s < 2; s++) {
#pragma unroll
      for (int kk = 0; kk < 4; kk++) {
        f32x4 sv = mfma16(ak0[s], *(const bf16x8*)&Qs2[(kk * 16 + lm) * PAD + lq * 8], zero);
        sv = mfma16(ak1[s], *(const bf16x8*)&Qs2[(kk * 16 + lm) * PAD + 32 + lq * 8], sv);
        float lv = lse[bh * SEQ + qc + kk * 16 + lm];
#pragma unroll
        for (int r = 0; r < 4; r++)
          pw[(lq * 4 + r) * PAD + kk * 16 + lm] = f2bf(__expf(betah * sv[r] - lv));
      }
      bf16x8 pa0 = *(const bf16x8*)&pw[lm * PAD + lq * 8];
      bf16x8 pa1 = *(const bf16x8*)&pw[lm * PAD + 32 + lq * 8];
#pragma unroll
      for (int nt = 0; nt < 4; nt++) {
        O[s][nt] = mfma16(pa0, *(const bf16x8*)&Qts[(nt * 16 + lm) * PAD + lq * 8], O[s][nt]);
        O[s][nt] = mfma16(pa1, *(const bf16x8*)&Qts[(nt * 16 + lm) * PAD + 32 + lq * 8], O[s][nt]);
      }
    }
  }
#pragma unroll
  for (int s = 0; s < 2; s++)
#pragma unroll
    for (int nt = 0; nt < 4; nt++)
#pragma unroll
      for (int r = 0; r < 4; r++) {
        int key = kt * 128 + s * 64 + w * 16 + lq * 4 + r;
        Dbuf[(size_t)(b * SEQ + key) * NUP + 768 + h * 64 + nt * 16 + lm] = f2bf(O[s][nt][r]);
      }
}

// ---------------- fused update + next-step LN ----------------
// x <- x - alpha * J_ln^T (x - sum_z G_z); then recompute mean/rstd/g for the NEXT step.
__global__ __launch_bounds__(256) void update_x(float* __restrict__ X, const float* __restrict__ G,
                                                float* __restrict__ meanb,
                                                float* __restrict__ rstdb,
                                                const float* __restrict__ gamma,
                                                const float* __restrict__ delta,
                                                us* __restrict__ g_bf) {
  int t = blockIdx.x, tid = threadIdx.x;
  __shared__ float sb[4];
  float mean = meanb[t], rstd = rstdb[t], gm = gamma[0];
  float* x = X + (size_t)t * DM;
  const float* g0 = G + (size_t)t * DM;
  const size_t GS = (size_t)T_TOK * DM;
  int i0 = tid, i1 = tid + 256, i2 = tid + 512;
  float x0 = x[i0], x1 = x[i1], x2 = x[i2];
  float gv0 = 0.f, gv1 = 0.f, gv2 = 0.f;
#pragma unroll
  for (int z = 0; z < SPLITK; z++) {
    gv0 += g0[i0 + z * GS];
    gv1 += g0[i1 + z * GS];
    gv2 += g0[i2 + z * GS];
  }
  float v0 = x0 - gv0, v1 = x1 - gv1, v2 = x2 - gv2;
  float n0 = (x0 - mean) * rstd, n1 = (x1 - mean) * rstd, n2 = (x2 - mean) * rstd;
  float s1 = block_sum(v0 + v1 + v2, sb, tid) * (1.0f / DM);
  float s2 = block_sum(v0 * n0 + v1 * n1 + v2 * n2, sb, tid) * (1.0f / DM);
  float c = ALPHA * gm * rstd;
  float y0 = x0 - c * (v0 - s1 - n0 * s2);
  float y1 = x1 - c * (v1 - s1 - n1 * s2);
  float y2 = x2 - c * (v2 - s1 - n2 * s2);
  x[i0] = y0; x[i1] = y1; x[i2] = y2;
  // --- fused LN for next step ---
  float mean2 = block_sum(y0 + y1 + y2, sb, tid) * (1.0f / DM);
  float d0 = y0 - mean2, d1 = y1 - mean2, d2 = y2 - mean2;
  float var2 = block_sum(d0 * d0 + d1 * d1 + d2 * d2, sb, tid) * (1.0f / DM);
  float rstd2 = rsqrtf(var2 + EPS);
  us* go = g_bf + (size_t)t * DM;
  go[i0] = f2bf(gm * d0 * rstd2 + delta[i0]);
  go[i1] = f2bf(gm * d1 * rstd2 + delta[i1]);
  go[i2] = f2bf(gm * d2 * rstd2 + delta[i2]);
  if (tid == 0) { meanb[t] = mean2; rstdb[t] = rstd2; }
}

// ---------------- host ----------------
extern "C" void kernel_launch(void* const* d_in, const int* in_sizes, int n_in,
                              void* d_out, int out_size, void* d_ws, size_t ws_size,
                              hipStream_t stream) {
  const float* x_in  = (const float*)d_in[0];
  const float* gamma = (const float*)d_in[1];
  const float* delta = (const float*)d_in[2];
  const float* Wq    = (const float*)d_in[3];
  const float* Wk    = (const float*)d_in[4];
  const float* beta  = (const float*)d_in[5];
  const float* xi    = (const float*)d_in[6];
  float* X = (float*)d_out;

  char* p = (char*)d_ws;
  auto carve = [&](size_t bytes) -> char* {
    char* q = p; p += (bytes + 255) & ~(size_t)255; return q;
  };
  us*    g_bf  = (us*)carve((size_t)T_TOK * DM * 2);
  float* meanb = (float*)carve((size_t)T_TOK * 4);
  float* rstdb = (float*)carve((size_t)T_TOK * 4);
  us*    QK    = (us*)carve((size_t)T_TOK * 1536 * 2);
  // G (SPLITK fp32 partials, 50 MB) aliases Qt/Kt (25 MB): transpose->attn
  // consume Qt/Kt strictly BEFORE the down-GEMM writes G, and update_x reads
  // G before the next step's transpose rewrites Qt/Kt.
  float* G     = (float*)carve((size_t)SPLITK * T_TOK * DM * 4);
  us*    Qt    = (us*)G;
  us*    Kt    = Qt + (size_t)NBH * 64 * 1024;
  float* lseb  = (float*)carve((size_t)NBH * SEQ * 4);
  us*    Dbuf  = (us*)carve((size_t)T_TOK * NUP * 2);
  us*    Wup   = (us*)carve((size_t)NUP * DM * 2);
  us*    WdT   = (us*)carve((size_t)DM * NUP * 2);

  hipMemcpyAsync(X, x_in, (size_t)T_TOK * DM * 4, hipMemcpyDeviceToDevice, stream);
  pack_w<<<(NUP * DM + 255) / 256, 256, 0, stream>>>(Wq, Wk, xi, Wup, WdT);
  ln_fwd<<<T_TOK, 256, 0, stream>>>(X, gamma, delta, g_bf, meanb, rstdb);

  for (int s = 0; s < NSTEPS; s++) {
    gemm_bt<0><<<dim3(64, 36, 1), 256, 0, stream>>>(g_bf, Wup, DM, DM, QK, Dbuf, nullptr);
    transpose_qk<<<dim3(NBH, 16, 2), 256, 0, stream>>>(QK, Qt, Kt);
    attn_fwd<<<dim3(NBH, 8), 256, 0, stream>>>(QK, Kt, beta, Dbuf, lseb);
    attn_bwd<<<dim3(NBH, 8), 256, 0, stream>>>(QK, Qt, lseb, beta, Dbuf);
    gemm_bt<1><<<dim3(64, 6, SPLITK), 256, 0, stream>>>(Dbuf, WdT, NUP, NUP / SPLITK,
                                                        nullptr, nullptr, G);
    update_x<<<T_TOK, 256, 0, stream>>>(X, G, meanb, rstdb, gamma, delta, g_bf);
  }
}

// Round 9
// 3669.090 us; speedup vs baseline: 1.0184x; 1.0184x over previous
//
#include <hip/hip_runtime.h>
#include <hip/hip_bf16.h>
#include <stdint.h>

// ---------------- constants ----------------
#define T_TOK 8192          // B*S tokens
#define DM    768
#define NH    12
#define DH    64
#define SEQ   1024
#define NBH   96            // B*NH
#define NMEM  3072
#define NUP   4608          // 768 (Q) + 768 (K) + 3072 (mem)
#define ALPHA 0.1f
#define EPS   1e-5f
#define NSTEPS 12
#define PAD   72            // LDS row stride (us) for attention 64-wide tiles
#define SPLITK 4            // down-GEMM split-K (r2-proven grid quantization at 256² tile)

typedef unsigned short us;
typedef __bf16 bf16x8 __attribute__((ext_vector_type(8)));
typedef float  f32x4  __attribute__((ext_vector_type(4)));

__device__ __forceinline__ us f2bf(float f) {          // RNE float->bf16
  uint32_t u = __builtin_bit_cast(uint32_t, f);
  u += 0x7fffu + ((u >> 16) & 1u);
  return (us)(u >> 16);
}

__device__ __forceinline__ f32x4 mfma16(bf16x8 a, bf16x8 b, f32x4 c) {
  return __builtin_amdgcn_mfma_f32_16x16x32_bf16(a, b, c, 0, 0, 0);
}

// async global->LDS, 16B per lane. LDS dest must be base + lane*16 in lane order.
__device__ __forceinline__ void gld16(const void* g, void* l) {
  __builtin_amdgcn_global_load_lds(
      (const __attribute__((address_space(1))) void*)(uintptr_t)g,
      (__attribute__((address_space(3))) void*)(uint32_t)(uintptr_t)l,
      16, 0, 0);
}

__device__ __forceinline__ float block_sum(float v, float* sb, int tid) {
#pragma unroll
  for (int d = 32; d >= 1; d >>= 1) v += __shfl_xor(v, d);
  __syncthreads();
  if ((tid & 63) == 0) sb[tid >> 6] = v;
  __syncthreads();
  return sb[0] + sb[1] + sb[2] + sb[3];
}

// ---------------- pack weights to bf16 (once per launch) ----------------
__global__ __launch_bounds__(256) void pack_w(const float* __restrict__ Wq,
                                              const float* __restrict__ Wk,
                                              const float* __restrict__ xi,
                                              us* __restrict__ Wup, us* __restrict__ WdT) {
  int idx = blockIdx.x * 256 + threadIdx.x;
  if (idx >= NUP * DM) return;
  int r = idx / DM, d = idx - r * DM;
  float v = (r < 768) ? Wq[idx] : (r < 1536 ? Wk[idx - 768 * DM] : xi[idx - 1536 * DM]);
  us h = f2bf(v);
  Wup[idx] = h;
  WdT[(size_t)d * NUP + r] = h;
}

// ---------------- LayerNorm fwd (only before step 0; later steps fuse LN into update) ----------
__global__ __launch_bounds__(256) void ln_fwd(const float* __restrict__ X,
                                              const float* __restrict__ gamma,
                                              const float* __restrict__ delta,
                                              us* __restrict__ g_bf,
                                              float* __restrict__ meanb, float* __restrict__ rstdb) {
  int t = blockIdx.x, tid = threadIdx.x;
  const float* x = X + (size_t)t * DM;
  __shared__ float sb[4];
  float v0 = x[tid], v1 = x[tid + 256], v2 = x[tid + 512];
  float mean = block_sum(v0 + v1 + v2, sb, tid) * (1.0f / DM);
  float d0 = v0 - mean, d1 = v1 - mean, d2 = v2 - mean;
  float var = block_sum(d0 * d0 + d1 * d1 + d2 * d2, sb, tid) * (1.0f / DM);
  float rstd = rsqrtf(var + EPS);
  float gm = gamma[0];
  us* go = g_bf + (size_t)t * DM;
  go[tid]       = f2bf(gm * d0 * rstd + delta[tid]);
  go[tid + 256] = f2bf(gm * d1 * rstd + delta[tid + 256]);
  go[tid + 512] = f2bf(gm * d2 * rstd + delta[tid + 512]);
  if (tid == 0) { meanb[t] = mean; rstdb[t] = rstd; }
}

// ---------------- UP-GEMM: 128x128, 4 waves (r5-proven: 91 us, FETCH 45 MB) ----------------
// 2-slot dbuf, 1 barrier/K-tile, involution swizzle, swapped-operand MFMA,
// packed 8B bf16 stores. MODE 0 only (QK + relu(mem) outputs).
__global__ __launch_bounds__(256, 4) void gemm_up(const us* __restrict__ A, const us* __restrict__ B,
                                                  us* __restrict__ QKout, us* __restrict__ Dout) {
  __shared__ us As[2 * 128 * 32];   // 16 KiB
  __shared__ us Bs[2 * 128 * 32];
  int tid = threadIdx.x;
  int w = tid >> 6, lane = tid & 63, lm = lane & 15, lq = lane >> 4;
  int wm = (w >> 1) * 64, wn = (w & 1) * 64;
  int m0 = blockIdx.x * 128, n0 = blockIdx.y * 128;
  const int NT = DM / 32;           // 24

  int sr  = tid >> 2;
  int k8s = (tid & 3) ^ ((tid >> 3) & 3);
  const us* pa = A + (size_t)(m0 + sr) * DM + k8s * 8;
  const us* pb = B + (size_t)(n0 + sr) * DM + k8s * 8;
  const size_t hstep = (size_t)64 * DM;
  us* dA0 = &As[tid * 8];
  us* dB0 = &Bs[tid * 8];

  int kx = (lq ^ ((lm >> 1) & 3)) * 8;
  const us* Ar = As + (wm + lm) * 32 + kx;
  const us* Br = Bs + (wn + lm) * 32 + kx;

  f32x4 zero4 = {0.f, 0.f, 0.f, 0.f};
  f32x4 acc[4][4];
#pragma unroll
  for (int i = 0; i < 4; i++)
#pragma unroll
    for (int j = 0; j < 4; j++) acc[i][j] = zero4;

#define STAGE(S, T) { gld16(pa + (size_t)(T) * 32,         dA0 + (S) * 4096);        \
                      gld16(pa + (size_t)(T) * 32 + hstep, dA0 + (S) * 4096 + 2048); \
                      gld16(pb + (size_t)(T) * 32,         dB0 + (S) * 4096);        \
                      gld16(pb + (size_t)(T) * 32 + hstep, dB0 + (S) * 4096 + 2048); }

  STAGE(0, 0);
  asm volatile("s_waitcnt vmcnt(0)" ::: "memory");
  __builtin_amdgcn_s_barrier();

#define ITER(T, S) {                                                            \
    if ((T) + 1 < NT) STAGE((S) ^ 1, (T) + 1);                                  \
    bf16x8 af_[4], bf_[4];                                                      \
    _Pragma("unroll") for (int x = 0; x < 4; x++)                               \
      af_[x] = *(const bf16x8*)(Ar + (S) * 4096 + x * 512);                     \
    _Pragma("unroll") for (int x = 0; x < 4; x++)                               \
      bf_[x] = *(const bf16x8*)(Br + (S) * 4096 + x * 512);                     \
    _Pragma("unroll") for (int mt = 0; mt < 4; mt++)                            \
      _Pragma("unroll") for (int nt = 0; nt < 4; nt++)                          \
        acc[mt][nt] = mfma16(bf_[nt], af_[mt], acc[mt][nt]);   /* swapped */    \
    if ((T) + 1 < NT) {                                                         \
      asm volatile("s_waitcnt lgkmcnt(0)" ::: "memory");                        \
      asm volatile("s_waitcnt vmcnt(0)" ::: "memory");                          \
      __builtin_amdgcn_s_barrier();                                             \
    }                                                                           \
  }

  for (int t = 0; t < NT; t += 2) {
    ITER(t,     0);
    ITER(t + 1, 1);
  }
#undef ITER
#undef STAGE

  // swapped layout: thread holds C[row = m0+wm+mt*16+lm][col = n0+wn+nt*16+lq*4 ..+3]
  int cb = wn + lq * 4;
  if (n0 < 1536) {
#pragma unroll
    for (int mt = 0; mt < 4; mt++) {
      us* rowp = QKout + (size_t)(m0 + wm + mt * 16 + lm) * 1536 + n0 + cb;
#pragma unroll
      for (int nt = 0; nt < 4; nt++) {
        f32x4 v = acc[mt][nt];
        uint2 p;
        p.x = (uint32_t)f2bf(v[0]) | ((uint32_t)f2bf(v[1]) << 16);
        p.y = (uint32_t)f2bf(v[2]) | ((uint32_t)f2bf(v[3]) << 16);
        *(uint2*)(rowp + nt * 16) = p;
      }
    }
  } else {
#pragma unroll
    for (int mt = 0; mt < 4; mt++) {
      us* rowp = Dout + (size_t)(m0 + wm + mt * 16 + lm) * NUP + n0 + cb;
#pragma unroll
      for (int nt = 0; nt < 4; nt++) {
        f32x4 v = acc[mt][nt];
        uint2 p;
        p.x = (uint32_t)f2bf(fmaxf(v[0], 0.f)) | ((uint32_t)f2bf(fmaxf(v[1], 0.f)) << 16);
        p.y = (uint32_t)f2bf(fmaxf(v[2], 0.f)) | ((uint32_t)f2bf(fmaxf(v[3], 0.f)) << 16);
        *(uint2*)(rowp + nt * 16) = p;
      }
    }
  }
}

// ---------------- DOWN-GEMM: 256x256, 8 waves, 3-slot ring (r2-proven structure) ----------
// Minimal-barrier: 12 ds_read -> 4 gld16 (tile t+2) -> 32 MFMA -> lgkmcnt(0)
// -> vmcnt(4) counted -> ONE s_barrier. Race ledger identical to r2 (WAR via
// lgkmcnt+barrier one iter before restage; RAW via vmcnt(4) draining tile t+1).
// r9 change vs r2: swapped-operand MFMA + coalesced f32x4 epilogue
// (128 scalar stores -> 32 vector stores). kchunk=1152, NT=36 (div by 3).
__global__ __launch_bounds__(512, 2) void gemm_dn(const us* __restrict__ A, const us* __restrict__ B,
                                                  int kchunk, float* __restrict__ Gout) {
  __shared__ us As[3 * 256 * 32];   // 48 KiB
  __shared__ us Bs[3 * 256 * 32];
  int tid = threadIdx.x;
  int w = tid >> 6, lane = tid & 63, lm = lane & 15, lq = lane >> 4;
  int wm = w >> 2, wn = w & 3;      // 2x4 wave grid; per-wave C = 128x64

  // XCD-aware bijective block swizzle (as measured in r2)
  int nwg  = gridDim.x * gridDim.y;
  int id   = blockIdx.y * gridDim.x + blockIdx.x;
  int qq   = nwg >> 3, rr = nwg & 7;
  int xcd  = id & 7, rank = id >> 3;
  int nid  = (xcd < rr ? xcd * (qq + 1) : rr * (qq + 1) + (xcd - rr) * qq) + rank;
  int bm   = nid % gridDim.x, bn = nid / gridDim.x;
  int m0 = bm * 256, n0 = bn * 256;
  int kbeg = blockIdx.z * kchunk;
  int NT = kchunk >> 5;             // 36

  int sr  = w * 16 + (lane >> 2);
  int k8s = (lane & 3) ^ ((lane >> 3) & 3);
  const us* pa = A + (size_t)(m0 + sr) * NUP + kbeg + k8s * 8;
  const us* pb = B + (size_t)(n0 + sr) * NUP + kbeg + k8s * 8;
  const size_t hstep = (size_t)128 * NUP;
  us* dA0 = &As[tid * 8];
  us* dB0 = &Bs[tid * 8];

  int kx   = (lq ^ ((lm >> 1) & 3)) * 8;
  int aoff = (wm * 128 + lm) * 32 + kx;
  int boff = (wn * 64  + lm) * 32 + kx;
  const us* Ar = As + aoff;
  const us* Br = Bs + boff;

  f32x4 zero4 = {0.f, 0.f, 0.f, 0.f};
  f32x4 acc[8][4];
#pragma unroll
  for (int i = 0; i < 8; i++)
#pragma unroll
    for (int j = 0; j < 4; j++) acc[i][j] = zero4;

#define STAGE_A(S, T) { gld16(pa + (size_t)(T) * 32,         dA0 + (S) * 8192); \
                        gld16(pa + (size_t)(T) * 32 + hstep, dA0 + (S) * 8192 + 4096); }
#define STAGE_B(S, T) { gld16(pb + (size_t)(T) * 32,         dB0 + (S) * 8192); \
                        gld16(pb + (size_t)(T) * 32 + hstep, dB0 + (S) * 8192 + 4096); }

  STAGE_A(0, 0); STAGE_B(0, 0);
  STAGE_A(1, 1); STAGE_B(1, 1);
  asm volatile("s_waitcnt vmcnt(4)" ::: "memory");
  __builtin_amdgcn_s_barrier();

#define ITER(T, S) {                                                            \
    bf16x8 af_[8], bf_[4];                                                      \
    _Pragma("unroll") for (int x = 0; x < 8; x++)                               \
      af_[x] = *(const bf16x8*)(Ar + (S) * 8192 + x * 512);                     \
    _Pragma("unroll") for (int x = 0; x < 4; x++)                               \
      bf_[x] = *(const bf16x8*)(Br + (S) * 8192 + x * 512);                     \
    if ((T) + 2 < NT) { STAGE_A(((S) + 2) % 3, (T) + 2);                        \
                        STAGE_B(((S) + 2) % 3, (T) + 2); }                      \
    _Pragma("unroll") for (int mt = 0; mt < 8; mt++)                            \
      _Pragma("unroll") for (int nt = 0; nt < 4; nt++)                          \
        acc[mt][nt] = mfma16(bf_[nt], af_[mt], acc[mt][nt]);   /* swapped */    \
    asm volatile("s_waitcnt lgkmcnt(0)" ::: "memory");                          \
    if ((T) + 2 < NT)      { asm volatile("s_waitcnt vmcnt(4)" ::: "memory"); } \
    else if ((T) + 1 < NT) { asm volatile("s_waitcnt vmcnt(0)" ::: "memory"); } \
    __builtin_amdgcn_s_barrier();                                               \
  }

  for (int t = 0; t < NT; t += 3) {
    ITER(t,     0);
    ITER(t + 1, 1);
    ITER(t + 2, 2);
  }
#undef ITER
#undef STAGE_A
#undef STAGE_B

  // swapped layout: thread holds C[row = m0+wm*128+mt*16+lm][col = n0+wn*64+nt*16+lq*4 ..+3]
  float* Gz = Gout + (size_t)blockIdx.z * T_TOK * DM;
  int cb = wn * 64 + lq * 4;
#pragma unroll
  for (int mt = 0; mt < 8; mt++) {
    float* rowp = Gz + (size_t)(m0 + wm * 128 + mt * 16 + lm) * DM + n0 + cb;
#pragma unroll
    for (int nt = 0; nt < 4; nt++)
      *(f32x4*)(rowp + nt * 16) = acc[mt][nt];
  }
}

// ---------------- transpose QK -> per-head Qt/Kt (dh-major, key contiguous) ----------------
__global__ __launch_bounds__(256) void transpose_qk(const us* __restrict__ QK,
                                                    us* __restrict__ Qt, us* __restrict__ Kt) {
  int bh = blockIdx.x, kt = blockIdx.y, which = blockIdx.z;
  int b = bh / NH, h = bh - b * NH;
  int tid = threadIdx.x;
  __shared__ us tile[64][72];
  int c0 = h * 64 + (which ? 768 : 0);
  us* dst = (which ? Kt : Qt) + (size_t)bh * 64 * 1024;
#pragma unroll
  for (int r = 0; r < 2; r++) {
    int key = r * 32 + (tid >> 3); int yb = (tid & 7) * 8;
    *(bf16x8*)&tile[key][yb] =
        *(const bf16x8*)&QK[(size_t)(b * SEQ + kt * 64 + key) * 1536 + c0 + yb];
  }
  __syncthreads();
#pragma unroll
  for (int r = 0; r < 2; r++) {
    int lin = r * 256 + tid; int y = lin >> 3; int kb = (lin & 7) * 8;
    __align__(16) us tmp[8];
#pragma unroll
    for (int j = 0; j < 8; j++) tmp[j] = tile[kb + j][y];
    *(bf16x8*)&dst[(size_t)y * 1024 + kt * 64 + kb] = *(bf16x8*)tmp;
  }
}

// ---------------- attention pass 1: Oq = softmax(beta QK^T) K (+lse) ----------------
// r9: reverted to the r7 64-row form (r8 QBLK=128 regressed -192 us:
// Ps-scratch serialization + occupancy loss beat the staging saving).
// No online max: |beta*A| << 1 (g is LayerNormed), exp cannot overflow.
__global__ __launch_bounds__(256) void attn_fwd(const us* __restrict__ QK, const us* __restrict__ Ktg,
                                                const float* __restrict__ beta,
                                                us* __restrict__ Dbuf, float* __restrict__ lse) {
  __shared__ us Qs[64 * PAD];
  __shared__ us Ks[64 * PAD];
  __shared__ us Kts[64 * PAD];
  __shared__ us Ps[4 * 16 * PAD];
  int bh = blockIdx.x, qt = blockIdx.y;
  int b = bh / NH, h = bh - b * NH;
  int tid = threadIdx.x, w = tid >> 6, lane = tid & 63, lm = lane & 15, lq = lane >> 4;
  float betah = beta[h];
#pragma unroll
  for (int r = 0; r < 2; r++) {
    int row = r * 32 + (tid >> 3); int yb = (tid & 7) * 8;
    *(bf16x8*)&Qs[row * PAD + yb] =
        *(const bf16x8*)&QK[(size_t)(b * SEQ + qt * 64 + row) * 1536 + h * 64 + yb];
  }
  __syncthreads();
  bf16x8 aq0 = *(const bf16x8*)&Qs[(w * 16 + lm) * PAD + lq * 8];
  bf16x8 aq1 = *(const bf16x8*)&Qs[(w * 16 + lm) * PAD + 32 + lq * 8];
  f32x4 zero = {0.f, 0.f, 0.f, 0.f};
  f32x4 O[4] = {zero, zero, zero, zero};
  float lacc[4] = {0.f, 0.f, 0.f, 0.f};
  us* pw = &Ps[w * 16 * PAD];

  for (int kc = 0; kc < SEQ; kc += 64) {
    __syncthreads();
#pragma unroll
    for (int r = 0; r < 2; r++) {
      int row = r * 32 + (tid >> 3); int yb = (tid & 7) * 8;
      *(bf16x8*)&Ks[row * PAD + yb] =
          *(const bf16x8*)&QK[(size_t)(b * SEQ + kc + row) * 1536 + 768 + h * 64 + yb];
      int lin = r * 256 + tid; int y = lin >> 3; int kb = (lin & 7) * 8;
      *(bf16x8*)&Kts[y * PAD + kb] =
          *(const bf16x8*)&Ktg[(size_t)(bh * 64 + y) * 1024 + kc + kb];
    }
    __syncthreads();
#pragma unroll
    for (int kk = 0; kk < 4; kk++) {
      f32x4 s = mfma16(aq0, *(const bf16x8*)&Ks[(kk * 16 + lm) * PAD + lq * 8], zero);
      s = mfma16(aq1, *(const bf16x8*)&Ks[(kk * 16 + lm) * PAD + 32 + lq * 8], s);
#pragma unroll
      for (int r = 0; r < 4; r++) {
        float p = __expf(betah * s[r]);
        lacc[r] += p;
        pw[(lq * 4 + r) * PAD + kk * 16 + lm] = f2bf(p);
      }
    }
    bf16x8 pa0 = *(const bf16x8*)&pw[lm * PAD + lq * 8];
    bf16x8 pa1 = *(const bf16x8*)&pw[lm * PAD + 32 + lq * 8];
#pragma unroll
    for (int nt = 0; nt < 4; nt++) {
      O[nt] = mfma16(pa0, *(const bf16x8*)&Kts[(nt * 16 + lm) * PAD + lq * 8], O[nt]);
      O[nt] = mfma16(pa1, *(const bf16x8*)&Kts[(nt * 16 + lm) * PAD + 32 + lq * 8], O[nt]);
    }
  }
  float l[4];
#pragma unroll
  for (int r = 0; r < 4; r++) {
    float v = lacc[r];
    v += __shfl_xor(v, 1); v += __shfl_xor(v, 2);
    v += __shfl_xor(v, 4); v += __shfl_xor(v, 8);
    l[r] = v;
  }
  float inv[4];
#pragma unroll
  for (int r = 0; r < 4; r++) inv[r] = 1.f / l[r];
#pragma unroll
  for (int nt = 0; nt < 4; nt++)
#pragma unroll
    for (int r = 0; r < 4; r++) {
      int q = qt * 64 + w * 16 + lq * 4 + r;
      Dbuf[(size_t)(b * SEQ + q) * NUP + h * 64 + nt * 16 + lm] = f2bf(O[nt][r] * inv[r]);
    }
  if (lm == 0) {
#pragma unroll
    for (int r = 0; r < 4; r++)
      lse[bh * SEQ + qt * 64 + w * 16 + lq * 4 + r] = __logf(l[r]);
  }
}

// ---------------- attention pass 2: Ok = P^T Q using stored lse ----------------
__global__ __launch_bounds__(256) void attn_bwd(const us* __restrict__ QK, const us* __restrict__ Qtg,
                                                const float* __restrict__ lse,
                                                const float* __restrict__ beta,
                                                us* __restrict__ Dbuf) {
  __shared__ us Ks2[64 * PAD];
  __shared__ us Qs2[64 * PAD];
  __shared__ us Qts[64 * PAD];
  __shared__ us Ps[4 * 16 * PAD];
  int bh = blockIdx.x, kt = blockIdx.y;
  int b = bh / NH, h = bh - b * NH;
  int tid = threadIdx.x, w = tid >> 6, lane = tid & 63, lm = lane & 15, lq = lane >> 4;
  float betah = beta[h];
#pragma unroll
  for (int r = 0; r < 2; r++) {
    int row = r * 32 + (tid >> 3); int yb = (tid & 7) * 8;
    *(bf16x8*)&Ks2[row * PAD + yb] =
        *(const bf16x8*)&QK[(size_t)(b * SEQ + kt * 64 + row) * 1536 + 768 + h * 64 + yb];
  }
  __syncthreads();
  bf16x8 ak0 = *(const bf16x8*)&Ks2[(w * 16 + lm) * PAD + lq * 8];
  bf16x8 ak1 = *(const bf16x8*)&Ks2[(w * 16 + lm) * PAD + 32 + lq * 8];
  f32x4 zero = {0.f, 0.f, 0.f, 0.f};
  f32x4 O[4] = {zero, zero, zero, zero};
  us* pw = &Ps[w * 16 * PAD];

  for (int qc = 0; qc < SEQ; qc += 64) {
    __syncthreads();
#pragma unroll
    for (int r = 0; r < 2; r++) {
      int row = r * 32 + (tid >> 3); int yb = (tid & 7) * 8;
      *(bf16x8*)&Qs2[row * PAD + yb] =
          *(const bf16x8*)&QK[(size_t)(b * SEQ + qc + row) * 1536 + h * 64 + yb];
      int lin = r * 256 + tid; int y = lin >> 3; int qb = (lin & 7) * 8;
      *(bf16x8*)&Qts[y * PAD + qb] =
          *(const bf16x8*)&Qtg[(size_t)(bh * 64 + y) * 1024 + qc + qb];
    }
    __syncthreads();
#pragma unroll
    for (int kk = 0; kk < 4; kk++) {
      f32x4 s = mfma16(ak0, *(const bf16x8*)&Qs2[(kk * 16 + lm) * PAD + lq * 8], zero);
      s = mfma16(ak1, *(const bf16x8*)&Qs2[(kk * 16 + lm) * PAD + 32 + lq * 8], s);
      float lv = lse[bh * SEQ + qc + kk * 16 + lm];
#pragma unroll
      for (int r = 0; r < 4; r++)
        pw[(lq * 4 + r) * PAD + kk * 16 + lm] = f2bf(__expf(betah * s[r] - lv));
    }
    bf16x8 pa0 = *(const bf16x8*)&pw[lm * PAD + lq * 8];
    bf16x8 pa1 = *(const bf16x8*)&pw[lm * PAD + 32 + lq * 8];
#pragma unroll
    for (int nt = 0; nt < 4; nt++) {
      O[nt] = mfma16(pa0, *(const bf16x8*)&Qts[(nt * 16 + lm) * PAD + lq * 8], O[nt]);
      O[nt] = mfma16(pa1, *(const bf16x8*)&Qts[(nt * 16 + lm) * PAD + 32 + lq * 8], O[nt]);
    }
  }
#pragma unroll
  for (int nt = 0; nt < 4; nt++)
#pragma unroll
    for (int r = 0; r < 4; r++) {
      int key = kt * 64 + w * 16 + lq * 4 + r;
      Dbuf[(size_t)(b * SEQ + key) * NUP + 768 + h * 64 + nt * 16 + lm] = f2bf(O[nt][r]);
    }
}

// ---------------- fused update + next-step LN ----------------
// x <- x - alpha * J_ln^T (x - sum_z G_z); then recompute mean/rstd/g for the NEXT step.
__global__ __launch_bounds__(256) void update_x(float* __restrict__ X, const float* __restrict__ G,
                                                float* __restrict__ meanb,
                                                float* __restrict__ rstdb,
                                                const float* __restrict__ gamma,
                                                const float* __restrict__ delta,
                                                us* __restrict__ g_bf) {
  int t = blockIdx.x, tid = threadIdx.x;
  __shared__ float sb[4];
  float mean = meanb[t], rstd = rstdb[t], gm = gamma[0];
  float* x = X + (size_t)t * DM;
  const float* g0 = G + (size_t)t * DM;
  const size_t GS = (size_t)T_TOK * DM;
  int i0 = tid, i1 = tid + 256, i2 = tid + 512;
  float x0 = x[i0], x1 = x[i1], x2 = x[i2];
  float gv0 = 0.f, gv1 = 0.f, gv2 = 0.f;
#pragma unroll
  for (int z = 0; z < SPLITK; z++) {
    gv0 += g0[i0 + z * GS];
    gv1 += g0[i1 + z * GS];
    gv2 += g0[i2 + z * GS];
  }
  float v0 = x0 - gv0, v1 = x1 - gv1, v2 = x2 - gv2;
  float n0 = (x0 - mean) * rstd, n1 = (x1 - mean) * rstd, n2 = (x2 - mean) * rstd;
  float s1 = block_sum(v0 + v1 + v2, sb, tid) * (1.0f / DM);
  float s2 = block_sum(v0 * n0 + v1 * n1 + v2 * n2, sb, tid) * (1.0f / DM);
  float c = ALPHA * gm * rstd;
  float y0 = x0 - c * (v0 - s1 - n0 * s2);
  float y1 = x1 - c * (v1 - s1 - n1 * s2);
  float y2 = x2 - c * (v2 - s1 - n2 * s2);
  x[i0] = y0; x[i1] = y1; x[i2] = y2;
  // --- fused LN for next step ---
  float mean2 = block_sum(y0 + y1 + y2, sb, tid) * (1.0f / DM);
  float d0 = y0 - mean2, d1 = y1 - mean2, d2 = y2 - mean2;
  float var2 = block_sum(d0 * d0 + d1 * d1 + d2 * d2, sb, tid) * (1.0f / DM);
  float rstd2 = rsqrtf(var2 + EPS);
  us* go = g_bf + (size_t)t * DM;
  go[i0] = f2bf(gm * d0 * rstd2 + delta[i0]);
  go[i1] = f2bf(gm * d1 * rstd2 + delta[i1]);
  go[i2] = f2bf(gm * d2 * rstd2 + delta[i2]);
  if (tid == 0) { meanb[t] = mean2; rstdb[t] = rstd2; }
}

// ---------------- host ----------------
extern "C" void kernel_launch(void* const* d_in, const int* in_sizes, int n_in,
                              void* d_out, int out_size, void* d_ws, size_t ws_size,
                              hipStream_t stream) {
  const float* x_in  = (const float*)d_in[0];
  const float* gamma = (const float*)d_in[1];
  const float* delta = (const float*)d_in[2];
  const float* Wq    = (const float*)d_in[3];
  const float* Wk    = (const float*)d_in[4];
  const float* beta  = (const float*)d_in[5];
  const float* xi    = (const float*)d_in[6];
  float* X = (float*)d_out;

  char* p = (char*)d_ws;
  auto carve = [&](size_t bytes) -> char* {
    char* q = p; p += (bytes + 255) & ~(size_t)255; return q;
  };
  us*    g_bf  = (us*)carve((size_t)T_TOK * DM * 2);
  float* meanb = (float*)carve((size_t)T_TOK * 4);
  float* rstdb = (float*)carve((size_t)T_TOK * 4);
  us*    QK    = (us*)carve((size_t)T_TOK * 1536 * 2);
  // G (SPLITK fp32 partials, 100 MB) aliases Qt/Kt (25 MB): transpose->attn
  // consume Qt/Kt strictly BEFORE the down-GEMM writes G, and update_x reads
  // G before the next step's transpose rewrites Qt/Kt.
  float* G     = (float*)carve((size_t)SPLITK * T_TOK * DM * 4);
  us*    Qt    = (us*)G;
  us*    Kt    = Qt + (size_t)NBH * 64 * 1024;
  float* lseb  = (float*)carve((size_t)NBH * SEQ * 4);
  us*    Dbuf  = (us*)carve((size_t)T_TOK * NUP * 2);
  us*    Wup   = (us*)carve((size_t)NUP * DM * 2);
  us*    WdT   = (us*)carve((size_t)DM * NUP * 2);

  hipMemcpyAsync(X, x_in, (size_t)T_TOK * DM * 4, hipMemcpyDeviceToDevice, stream);
  pack_w<<<(NUP * DM + 255) / 256, 256, 0, stream>>>(Wq, Wk, xi, Wup, WdT);
  ln_fwd<<<T_TOK, 256, 0, stream>>>(X, gamma, delta, g_bf, meanb, rstdb);

  for (int s = 0; s < NSTEPS; s++) {
    gemm_up<<<dim3(64, 36), 256, 0, stream>>>(g_bf, Wup, QK, Dbuf);
    transpose_qk<<<dim3(NBH, 16, 2), 256, 0, stream>>>(QK, Qt, Kt);
    attn_fwd<<<dim3(NBH, 16), 256, 0, stream>>>(QK, Kt, beta, Dbuf, lseb);
    attn_bwd<<<dim3(NBH, 16), 256, 0, stream>>>(QK, Qt, lseb, beta, Dbuf);
    gemm_dn<<<dim3(32, 3, SPLITK), 512, 0, stream>>>(Dbuf, WdT, NUP / SPLITK, G);
    update_x<<<T_TOK, 256, 0, stream>>>(X, G, meanb, rstdb, gamma, delta, g_bf);
  }
}

// Round 10
// 3296.593 us; speedup vs baseline: 1.1335x; 1.1130x over previous
//
#include <hip/hip_runtime.h>
#include <hip/hip_bf16.h>
#include <stdint.h>

// ---------------- constants ----------------
#define T_TOK 8192          // B*S tokens
#define DM    768
#define NH    12
#define DH    64
#define SEQ   1024
#define NBH   96            // B*NH
#define NMEM  3072
#define NUP   4608          // 768 (Q) + 768 (K) + 3072 (mem)
#define ALPHA 0.1f
#define EPS   1e-5f
#define NSTEPS 12
#define PAD   72            // LDS row stride (us) for attention 64-wide tiles
#define SPLITK 2            // r10: was 4 on this base. Halves fp32 partial traffic
                            // (100->50 MB/step each way) and makes the down grid
                            // 32x3x2=192 blocks = one full round at 1 block/CU
                            // (was 384 = 1.5 rounds). Mechanism proven r6->r7.

typedef unsigned short us;
typedef __bf16 bf16x8 __attribute__((ext_vector_type(8)));
typedef float  f32x4  __attribute__((ext_vector_type(4)));

__device__ __forceinline__ us f2bf(float f) {          // RNE float->bf16
  uint32_t u = __builtin_bit_cast(uint32_t, f);
  u += 0x7fffu + ((u >> 16) & 1u);
  return (us)(u >> 16);
}

__device__ __forceinline__ f32x4 mfma16(bf16x8 a, bf16x8 b, f32x4 c) {
  return __builtin_amdgcn_mfma_f32_16x16x32_bf16(a, b, c, 0, 0, 0);
}

// async global->LDS, 16B per lane. LDS dest must be base + lane*16 in lane order.
__device__ __forceinline__ void gld16(const void* g, void* l) {
  __builtin_amdgcn_global_load_lds(
      (const __attribute__((address_space(1))) void*)(uintptr_t)g,
      (__attribute__((address_space(3))) void*)(uint32_t)(uintptr_t)l,
      16, 0, 0);
}

__device__ __forceinline__ float block_sum(float v, float* sb, int tid) {
#pragma unroll
  for (int d = 32; d >= 1; d >>= 1) v += __shfl_xor(v, d);
  __syncthreads();
  if ((tid & 63) == 0) sb[tid >> 6] = v;
  __syncthreads();
  return sb[0] + sb[1] + sb[2] + sb[3];
}

// ---------------- pack weights to bf16 (once per launch) ----------------
__global__ __launch_bounds__(256) void pack_w(const float* __restrict__ Wq,
                                              const float* __restrict__ Wk,
                                              const float* __restrict__ xi,
                                              us* __restrict__ Wup, us* __restrict__ WdT) {
  int idx = blockIdx.x * 256 + threadIdx.x;
  if (idx >= NUP * DM) return;
  int r = idx / DM, d = idx - r * DM;
  float v = (r < 768) ? Wq[idx] : (r < 1536 ? Wk[idx - 768 * DM] : xi[idx - 1536 * DM]);
  us h = f2bf(v);
  Wup[idx] = h;
  WdT[(size_t)d * NUP + r] = h;
}

// ---------------- LayerNorm fwd (only before step 0; later steps fuse LN into update) ----------
__global__ __launch_bounds__(256) void ln_fwd(const float* __restrict__ X,
                                              const float* __restrict__ gamma,
                                              const float* __restrict__ delta,
                                              us* __restrict__ g_bf,
                                              float* __restrict__ meanb, float* __restrict__ rstdb) {
  int t = blockIdx.x, tid = threadIdx.x;
  const float* x = X + (size_t)t * DM;
  __shared__ float sb[4];
  float v0 = x[tid], v1 = x[tid + 256], v2 = x[tid + 512];
  float mean = block_sum(v0 + v1 + v2, sb, tid) * (1.0f / DM);
  float d0 = v0 - mean, d1 = v1 - mean, d2 = v2 - mean;
  float var = block_sum(d0 * d0 + d1 * d1 + d2 * d2, sb, tid) * (1.0f / DM);
  float rstd = rsqrtf(var + EPS);
  float gm = gamma[0];
  us* go = g_bf + (size_t)t * DM;
  go[tid]       = f2bf(gm * d0 * rstd + delta[tid]);
  go[tid + 256] = f2bf(gm * d1 * rstd + delta[tid + 256]);
  go[tid + 512] = f2bf(gm * d2 * rstd + delta[tid + 512]);
  if (tid == 0) { meanb[t] = mean; rstdb[t] = rstd; }
}

// ---------------- GEMM: C = A * B^T (bf16 in, fp32 acc) ----------------
// EXACT round-2 structure (best measured total: 3479 us). 256x256 tile,
// 512 threads (8 waves, 2M x 4N), BK=32, 3-slot LDS ring, minimal-barrier:
//   12 ds_read (frags upfront) -> 4 global_load_lds (tile t+2) -> 32 MFMA
//   -> lgkmcnt(0) -> counted vmcnt(4) -> ONE s_barrier per K-tile.
// Race ledger:
//  - WAR slot (t+2)%3 (holds tile t-1): every wave drained its t-1 reads via
//    lgkmcnt(0) before the t-1 trailing barrier; stages of tile t come after.
//  - RAW slot (t+1)%3: vmcnt(4) at end of tile t drains tile t+1's 4 loads
//    (oldest outstanding); barrier publishes cross-wave.
// Involution swizzle on pre-swizzled global source + ds_read offset
// (verified SQ_LDS_BANK_CONFLICT == 0). Requires kchunk % 96 == 0:
// up 768 ok, down 2304 ok (NT=72).
template <int MODE>
__global__ __launch_bounds__(512, 2) void gemm_bt(const us* __restrict__ A, const us* __restrict__ B,
                                                  int Kstride, int kchunk, us* __restrict__ QKout,
                                                  us* __restrict__ Dout, float* __restrict__ Gout) {
  __shared__ us As[3 * 256 * 32];   // 48 KiB: [slot][row 256][k8 0..3][8 us]
  __shared__ us Bs[3 * 256 * 32];   // 48 KiB
  int tid = threadIdx.x;
  int w = tid >> 6, lane = tid & 63, lm = lane & 15, lq = lane >> 4;
  int wm = w >> 2, wn = w & 3;      // 2 x 4 wave grid; per-wave C = 128x64

  // XCD-aware bijective block swizzle (8 XCDs; nwg = 96 divisible by 8)
  int nwg  = gridDim.x * gridDim.y;
  int id   = blockIdx.y * gridDim.x + blockIdx.x;
  int qq   = nwg >> 3, rr = nwg & 7;
  int xcd  = id & 7, rank = id >> 3;
  int nid  = (xcd < rr ? xcd * (qq + 1) : rr * (qq + 1) + (xcd - rr) * qq) + rank;
  int bm   = nid % gridDim.x, bn = nid / gridDim.x;
  int m0 = bm * 256, n0 = bn * 256;
  int kbeg = blockIdx.z * kchunk;
  int NT = kchunk >> 5;             // K tiles of 32; divisible by 3

  int sr  = w * 16 + (lane >> 2);
  int k8s = (lane & 3) ^ ((lane >> 3) & 3);
  const us* pa = A + (size_t)(m0 + sr) * Kstride + kbeg + k8s * 8;
  const us* pb = B + (size_t)(n0 + sr) * Kstride + kbeg + k8s * 8;
  const size_t hstep = (size_t)128 * Kstride;
  us* dA0 = &As[tid * 8];           // linear LDS dest: slot*8192 + j*4096 + tid*8
  us* dB0 = &Bs[tid * 8];

  int kx   = (lq ^ ((lm >> 1) & 3)) * 8;   // row bits [2:1] == lm bits [2:1]
  int aoff = (wm * 128 + lm) * 32 + kx;
  int boff = (wn * 64  + lm) * 32 + kx;
  const us* Ar = As + aoff;         // frag mt at Ar[S*8192 + mt*512]
  const us* Br = Bs + boff;         // frag nt at Br[S*8192 + nt*512]

  f32x4 zero4 = {0.f, 0.f, 0.f, 0.f};
  f32x4 acc[8][4];
#pragma unroll
  for (int i = 0; i < 8; i++)
#pragma unroll
    for (int j = 0; j < 4; j++) acc[i][j] = zero4;

#define STAGE_A(S, T) { gld16(pa + (size_t)(T) * 32,         dA0 + (S) * 8192); \
                        gld16(pa + (size_t)(T) * 32 + hstep, dA0 + (S) * 8192 + 4096); }
#define STAGE_B(S, T) { gld16(pb + (size_t)(T) * 32,         dB0 + (S) * 8192); \
                        gld16(pb + (size_t)(T) * 32 + hstep, dB0 + (S) * 8192 + 4096); }

  // ---- prologue: tile0 -> slot0, tile1 -> slot1 (issue order matters for vmcnt)
  STAGE_A(0, 0); STAGE_B(0, 0);
  STAGE_A(1, 1); STAGE_B(1, 1);
  asm volatile("s_waitcnt vmcnt(4)" ::: "memory");   // tile0 landed; tile1 in flight
  __builtin_amdgcn_s_barrier();

#define ITER(T, S) {                                                            \
    bf16x8 af_[8], bf_[4];                                                      \
    _Pragma("unroll") for (int x = 0; x < 8; x++)                               \
      af_[x] = *(const bf16x8*)(Ar + (S) * 8192 + x * 512);                     \
    _Pragma("unroll") for (int x = 0; x < 4; x++)                               \
      bf_[x] = *(const bf16x8*)(Br + (S) * 8192 + x * 512);                     \
    if ((T) + 2 < NT) { STAGE_A(((S) + 2) % 3, (T) + 2);                        \
                        STAGE_B(((S) + 2) % 3, (T) + 2); }                      \
    _Pragma("unroll") for (int mt = 0; mt < 8; mt++)                            \
      _Pragma("unroll") for (int nt = 0; nt < 4; nt++)                          \
        acc[mt][nt] = mfma16(af_[mt], bf_[nt], acc[mt][nt]);                    \
    asm volatile("s_waitcnt lgkmcnt(0)" ::: "memory");                          \
    if ((T) + 2 < NT)      { asm volatile("s_waitcnt vmcnt(4)" ::: "memory"); } \
    else if ((T) + 1 < NT) { asm volatile("s_waitcnt vmcnt(0)" ::: "memory"); } \
    __builtin_amdgcn_s_barrier();                                               \
  }

  for (int t = 0; t < NT; t += 3) {
    ITER(t,     0);
    ITER(t + 1, 1);
    ITER(t + 2, 2);
  }
#undef ITER
#undef STAGE_A
#undef STAGE_B

  // ---- epilogue: C layout col = lane&15, row = lq*4 + r
  float* Gz = (MODE == 1) ? Gout + (size_t)blockIdx.z * T_TOK * DM : nullptr;
#pragma unroll
  for (int mt = 0; mt < 8; mt++) {
    int row = m0 + wm * 128 + mt * 16 + lq * 4;
#pragma unroll
    for (int nt = 0; nt < 4; nt++) {
      int col = n0 + wn * 64 + nt * 16 + lm;
#pragma unroll
      for (int r = 0; r < 4; r++) {
        float v = acc[mt][nt][r];
        if (MODE == 0) {
          if (col < 1536) QKout[(size_t)(row + r) * 1536 + col] = f2bf(v);
          else            Dout[(size_t)(row + r) * NUP + col]   = f2bf(fmaxf(v, 0.f));
        } else {
          Gz[(size_t)(row + r) * DM + col] = v;
        }
      }
    }
  }
}

// ---------------- transpose QK -> per-head Qt/Kt (dh-major, key contiguous) ----------------
__global__ __launch_bounds__(256) void transpose_qk(const us* __restrict__ QK,
                                                    us* __restrict__ Qt, us* __restrict__ Kt) {
  int bh = blockIdx.x, kt = blockIdx.y, which = blockIdx.z;
  int b = bh / NH, h = bh - b * NH;
  int tid = threadIdx.x;
  __shared__ us tile[64][72];
  int c0 = h * 64 + (which ? 768 : 0);
  us* dst = (which ? Kt : Qt) + (size_t)bh * 64 * 1024;
#pragma unroll
  for (int r = 0; r < 2; r++) {
    int key = r * 32 + (tid >> 3); int yb = (tid & 7) * 8;
    *(bf16x8*)&tile[key][yb] =
        *(const bf16x8*)&QK[(size_t)(b * SEQ + kt * 64 + key) * 1536 + c0 + yb];
  }
  __syncthreads();
#pragma unroll
  for (int r = 0; r < 2; r++) {
    int lin = r * 256 + tid; int y = lin >> 3; int kb = (lin & 7) * 8;
    __align__(16) us tmp[8];
#pragma unroll
    for (int j = 0; j < 8; j++) tmp[j] = tile[kb + j][y];
    *(bf16x8*)&dst[(size_t)y * 1024 + kt * 64 + kb] = *(bf16x8*)tmp;
  }
}

// ---------------- attention pass 1: Oq = softmax(beta QK^T) K (+lse) ----------------
// No online max: |beta*A| << 1 (g is LayerNormed, |q|,|k| ~ 2.5, beta=1/8), exp cannot overflow.
__global__ __launch_bounds__(256) void attn_fwd(const us* __restrict__ QK, const us* __restrict__ Ktg,
                                                const float* __restrict__ beta,
                                                us* __restrict__ Dbuf, float* __restrict__ lse) {
  __shared__ us Qs[64 * PAD];
  __shared__ us Ks[64 * PAD];
  __shared__ us Kts[64 * PAD];
  __shared__ us Ps[4 * 16 * PAD];
  int bh = blockIdx.x, qt = blockIdx.y;
  int b = bh / NH, h = bh - b * NH;
  int tid = threadIdx.x, w = tid >> 6, lane = tid & 63, lm = lane & 15, lq = lane >> 4;
  float betah = beta[h];
#pragma unroll
  for (int r = 0; r < 2; r++) {
    int row = r * 32 + (tid >> 3); int yb = (tid & 7) * 8;
    *(bf16x8*)&Qs[row * PAD + yb] =
        *(const bf16x8*)&QK[(size_t)(b * SEQ + qt * 64 + row) * 1536 + h * 64 + yb];
  }
  __syncthreads();
  bf16x8 aq0 = *(const bf16x8*)&Qs[(w * 16 + lm) * PAD + lq * 8];
  bf16x8 aq1 = *(const bf16x8*)&Qs[(w * 16 + lm) * PAD + 32 + lq * 8];
  f32x4 zero = {0.f, 0.f, 0.f, 0.f};
  f32x4 O[4] = {zero, zero, zero, zero};
  float lacc[4] = {0.f, 0.f, 0.f, 0.f};
  us* pw = &Ps[w * 16 * PAD];

  for (int kc = 0; kc < SEQ; kc += 64) {
    __syncthreads();
#pragma unroll
    for (int r = 0; r < 2; r++) {
      int row = r * 32 + (tid >> 3); int yb = (tid & 7) * 8;
      *(bf16x8*)&Ks[row * PAD + yb] =
          *(const bf16x8*)&QK[(size_t)(b * SEQ + kc + row) * 1536 + 768 + h * 64 + yb];
      int lin = r * 256 + tid; int y = lin >> 3; int kb = (lin & 7) * 8;
      *(bf16x8*)&Kts[y * PAD + kb] =
          *(const bf16x8*)&Ktg[(size_t)(bh * 64 + y) * 1024 + kc + kb];
    }
    __syncthreads();
#pragma unroll
    for (int kk = 0; kk < 4; kk++) {
      f32x4 s = mfma16(aq0, *(const bf16x8*)&Ks[(kk * 16 + lm) * PAD + lq * 8], zero);
      s = mfma16(aq1, *(const bf16x8*)&Ks[(kk * 16 + lm) * PAD + 32 + lq * 8], s);
#pragma unroll
      for (int r = 0; r < 4; r++) {
        float p = __expf(betah * s[r]);
        lacc[r] += p;
        pw[(lq * 4 + r) * PAD + kk * 16 + lm] = f2bf(p);
      }
    }
    bf16x8 pa0 = *(const bf16x8*)&pw[lm * PAD + lq * 8];
    bf16x8 pa1 = *(const bf16x8*)&pw[lm * PAD + 32 + lq * 8];
#pragma unroll
    for (int nt = 0; nt < 4; nt++) {
      O[nt] = mfma16(pa0, *(const bf16x8*)&Kts[(nt * 16 + lm) * PAD + lq * 8], O[nt]);
      O[nt] = mfma16(pa1, *(const bf16x8*)&Kts[(nt * 16 + lm) * PAD + 32 + lq * 8], O[nt]);
    }
  }
  float l[4];
#pragma unroll
  for (int r = 0; r < 4; r++) {
    float v = lacc[r];
    v += __shfl_xor(v, 1); v += __shfl_xor(v, 2);
    v += __shfl_xor(v, 4); v += __shfl_xor(v, 8);
    l[r] = v;
  }
  float inv[4];
#pragma unroll
  for (int r = 0; r < 4; r++) inv[r] = 1.f / l[r];
#pragma unroll
  for (int nt = 0; nt < 4; nt++)
#pragma unroll
    for (int r = 0; r < 4; r++) {
      int q = qt * 64 + w * 16 + lq * 4 + r;
      Dbuf[(size_t)(b * SEQ + q) * NUP + h * 64 + nt * 16 + lm] = f2bf(O[nt][r] * inv[r]);
    }
  if (lm == 0) {
#pragma unroll
    for (int r = 0; r < 4; r++)
      lse[bh * SEQ + qt * 64 + w * 16 + lq * 4 + r] = __logf(l[r]);
  }
}

// ---------------- attention pass 2: Ok = P^T Q using stored lse ----------------
__global__ __launch_bounds__(256) void attn_bwd(const us* __restrict__ QK, const us* __restrict__ Qtg,
                                                const float* __restrict__ lse,
                                                const float* __restrict__ beta,
                                                us* __restrict__ Dbuf) {
  __shared__ us Ks2[64 * PAD];
  __shared__ us Qs2[64 * PAD];
  __shared__ us Qts[64 * PAD];
  __shared__ us Ps[4 * 16 * PAD];
  int bh = blockIdx.x, kt = blockIdx.y;
  int b = bh / NH, h = bh - b * NH;
  int tid = threadIdx.x, w = tid >> 6, lane = tid & 63, lm = lane & 15, lq = lane >> 4;
  float betah = beta[h];
#pragma unroll
  for (int r = 0; r < 2; r++) {
    int row = r * 32 + (tid >> 3); int yb = (tid & 7) * 8;
    *(bf16x8*)&Ks2[row * PAD + yb] =
        *(const bf16x8*)&QK[(size_t)(b * SEQ + kt * 64 + row) * 1536 + 768 + h * 64 + yb];
  }
  __syncthreads();
  bf16x8 ak0 = *(const bf16x8*)&Ks2[(w * 16 + lm) * PAD + lq * 8];
  bf16x8 ak1 = *(const bf16x8*)&Ks2[(w * 16 + lm) * PAD + 32 + lq * 8];
  f32x4 zero = {0.f, 0.f, 0.f, 0.f};
  f32x4 O[4] = {zero, zero, zero, zero};
  us* pw = &Ps[w * 16 * PAD];

  for (int qc = 0; qc < SEQ; qc += 64) {
    __syncthreads();
#pragma unroll
    for (int r = 0; r < 2; r++) {
      int row = r * 32 + (tid >> 3); int yb = (tid & 7) * 8;
      *(bf16x8*)&Qs2[row * PAD + yb] =
          *(const bf16x8*)&QK[(size_t)(b * SEQ + qc + row) * 1536 + h * 64 + yb];
      int lin = r * 256 + tid; int y = lin >> 3; int qb = (lin & 7) * 8;
      *(bf16x8*)&Qts[y * PAD + qb] =
          *(const bf16x8*)&Qtg[(size_t)(bh * 64 + y) * 1024 + qc + qb];
    }
    __syncthreads();
#pragma unroll
    for (int kk = 0; kk < 4; kk++) {
      f32x4 s = mfma16(ak0, *(const bf16x8*)&Qs2[(kk * 16 + lm) * PAD + lq * 8], zero);
      s = mfma16(ak1, *(const bf16x8*)&Qs2[(kk * 16 + lm) * PAD + 32 + lq * 8], s);
      float lv = lse[bh * SEQ + qc + kk * 16 + lm];
#pragma unroll
      for (int r = 0; r < 4; r++)
        pw[(lq * 4 + r) * PAD + kk * 16 + lm] = f2bf(__expf(betah * s[r] - lv));
    }
    bf16x8 pa0 = *(const bf16x8*)&pw[lm * PAD + lq * 8];
    bf16x8 pa1 = *(const bf16x8*)&pw[lm * PAD + 32 + lq * 8];
#pragma unroll
    for (int nt = 0; nt < 4; nt++) {
      O[nt] = mfma16(pa0, *(const bf16x8*)&Qts[(nt * 16 + lm) * PAD + lq * 8], O[nt]);
      O[nt] = mfma16(pa1, *(const bf16x8*)&Qts[(nt * 16 + lm) * PAD + 32 + lq * 8], O[nt]);
    }
  }
#pragma unroll
  for (int nt = 0; nt < 4; nt++)
#pragma unroll
    for (int r = 0; r < 4; r++) {
      int key = kt * 64 + w * 16 + lq * 4 + r;
      Dbuf[(size_t)(b * SEQ + key) * NUP + 768 + h * 64 + nt * 16 + lm] = f2bf(O[nt][r]);
    }
}

// ---------------- fused update + next-step LN ----------------
// x <- x - alpha * J_ln^T (x - sum_z G_z); then recompute mean/rstd/g for the NEXT step.
__global__ __launch_bounds__(256) void update_x(float* __restrict__ X, const float* __restrict__ G,
                                                float* __restrict__ meanb,
                                                float* __restrict__ rstdb,
                                                const float* __restrict__ gamma,
                                                const float* __restrict__ delta,
                                                us* __restrict__ g_bf) {
  int t = blockIdx.x, tid = threadIdx.x;
  __shared__ float sb[4];
  float mean = meanb[t], rstd = rstdb[t], gm = gamma[0];
  float* x = X + (size_t)t * DM;
  const float* g0 = G + (size_t)t * DM;
  const size_t GS = (size_t)T_TOK * DM;
  int i0 = tid, i1 = tid + 256, i2 = tid + 512;
  float x0 = x[i0], x1 = x[i1], x2 = x[i2];
  float gv0 = 0.f, gv1 = 0.f, gv2 = 0.f;
#pragma unroll
  for (int z = 0; z < SPLITK; z++) {
    gv0 += g0[i0 + z * GS];
    gv1 += g0[i1 + z * GS];
    gv2 += g0[i2 + z * GS];
  }
  float v0 = x0 - gv0, v1 = x1 - gv1, v2 = x2 - gv2;
  float n0 = (x0 - mean) * rstd, n1 = (x1 - mean) * rstd, n2 = (x2 - mean) * rstd;
  float s1 = block_sum(v0 + v1 + v2, sb, tid) * (1.0f / DM);
  float s2 = block_sum(v0 * n0 + v1 * n1 + v2 * n2, sb, tid) * (1.0f / DM);
  float c = ALPHA * gm * rstd;
  float y0 = x0 - c * (v0 - s1 - n0 * s2);
  float y1 = x1 - c * (v1 - s1 - n1 * s2);
  float y2 = x2 - c * (v2 - s1 - n2 * s2);
  x[i0] = y0; x[i1] = y1; x[i2] = y2;
  // --- fused LN for next step ---
  float mean2 = block_sum(y0 + y1 + y2, sb, tid) * (1.0f / DM);
  float d0 = y0 - mean2, d1 = y1 - mean2, d2 = y2 - mean2;
  float var2 = block_sum(d0 * d0 + d1 * d1 + d2 * d2, sb, tid) * (1.0f / DM);
  float rstd2 = rsqrtf(var2 + EPS);
  us* go = g_bf + (size_t)t * DM;
  go[i0] = f2bf(gm * d0 * rstd2 + delta[i0]);
  go[i1] = f2bf(gm * d1 * rstd2 + delta[i1]);
  go[i2] = f2bf(gm * d2 * rstd2 + delta[i2]);
  if (tid == 0) { meanb[t] = mean2; rstdb[t] = rstd2; }
}

// ---------------- host ----------------
extern "C" void kernel_launch(void* const* d_in, const int* in_sizes, int n_in,
                              void* d_out, int out_size, void* d_ws, size_t ws_size,
                              hipStream_t stream) {
  const float* x_in  = (const float*)d_in[0];
  const float* gamma = (const float*)d_in[1];
  const float* delta = (const float*)d_in[2];
  const float* Wq    = (const float*)d_in[3];
  const float* Wk    = (const float*)d_in[4];
  const float* beta  = (const float*)d_in[5];
  const float* xi    = (const float*)d_in[6];
  float* X = (float*)d_out;

  char* p = (char*)d_ws;
  auto carve = [&](size_t bytes) -> char* {
    char* q = p; p += (bytes + 255) & ~(size_t)255; return q;
  };
  us*    g_bf  = (us*)carve((size_t)T_TOK * DM * 2);
  float* meanb = (float*)carve((size_t)T_TOK * 4);
  float* rstdb = (float*)carve((size_t)T_TOK * 4);
  us*    QK    = (us*)carve((size_t)T_TOK * 1536 * 2);
  // G (SPLITK fp32 partials, 50 MB) aliases Qt/Kt (25 MB): transpose->attn
  // consume Qt/Kt strictly BEFORE the down-GEMM writes G, and update_x reads
  // G before the next step's transpose rewrites Qt/Kt.
  float* G     = (float*)carve((size_t)SPLITK * T_TOK * DM * 4);
  us*    Qt    = (us*)G;
  us*    Kt    = Qt + (size_t)NBH * 64 * 1024;
  float* lseb  = (float*)carve((size_t)NBH * SEQ * 4);
  us*    Dbuf  = (us*)carve((size_t)T_TOK * NUP * 2);
  us*    Wup   = (us*)carve((size_t)NUP * DM * 2);
  us*    WdT   = (us*)carve((size_t)DM * NUP * 2);

  hipMemcpyAsync(X, x_in, (size_t)T_TOK * DM * 4, hipMemcpyDeviceToDevice, stream);
  pack_w<<<(NUP * DM + 255) / 256, 256, 0, stream>>>(Wq, Wk, xi, Wup, WdT);
  ln_fwd<<<T_TOK, 256, 0, stream>>>(X, gamma, delta, g_bf, meanb, rstdb);

  for (int s = 0; s < NSTEPS; s++) {
    gemm_bt<0><<<dim3(32, 18, 1), 512, 0, stream>>>(g_bf, Wup, DM, DM, QK, Dbuf, nullptr);
    transpose_qk<<<dim3(NBH, 16, 2), 256, 0, stream>>>(QK, Qt, Kt);
    attn_fwd<<<dim3(NBH, 16), 256, 0, stream>>>(QK, Kt, beta, Dbuf, lseb);
    attn_bwd<<<dim3(NBH, 16), 256, 0, stream>>>(QK, Qt, lseb, beta, Dbuf);
    gemm_bt<1><<<dim3(32, 3, SPLITK), 512, 0, stream>>>(Dbuf, WdT, NUP, NUP / SPLITK,
                                                        nullptr, nullptr, G);
    update_x<<<T_TOK, 256, 0, stream>>>(X, G, meanb, rstdb, gamma, delta, g_bf);
  }
}